// Round 16
// baseline (101.637 us; speedup 1.0000x reference)
//
#include <hip/hip_runtime.h>

#define CDIM 64
#define KCODES 1024
#define ZQ_ELEMS (32 * 64 * 64 * 64)  // 8388608
#define NROWS 131072
#define FLT_BIG 3.402823466e38f
#define RPB 64                        // rows per block
#define NBLK (NROWS / RPB)            // 2048
#define CSTRIDE 97                    // sKey row stride (floats); 96 slots used
#define DELTA 5e-4f                   // screen slack; err bound ~2e-4 (z_lo+e_lo dropped)

// ws layout: [0,16KB) part | [16KB,20KB) Bsq | [32KB,+128KB) e1 | +2KB overread pad after
#define WS_BSQ_OFF 16384
#define WS_E1_OFF  32768

typedef __bf16 bf16x8 __attribute__((ext_vector_type(8)));
typedef float  f32x4  __attribute__((ext_vector_type(4)));

// numpy-exact pairwise sum of squares (8 accumulators, numpy pairwise order)
__device__ __forceinline__ float pairwise_sq64(const float* v) {
    float r[8];
    #pragma unroll
    for (int j = 0; j < 8; ++j) r[j] = __fmul_rn(v[j], v[j]);
    #pragma unroll
    for (int m = 1; m < 8; ++m) {
        #pragma unroll
        for (int j = 0; j < 8; ++j)
            r[j] = __fadd_rn(r[j], __fmul_rn(v[8 * m + j], v[8 * m + j]));
    }
    return __fadd_rn(__fadd_rn(__fadd_rn(r[0], r[1]), __fadd_rn(r[2], r[3])),
                     __fadd_rn(__fadd_rn(r[4], r[5]), __fadd_rn(r[6], r[7])));
}

// ---------------- prep: exact code norms + bf16 codebook, B-fragment layout ----
__global__ __launch_bounds__(256) void vq_prep(const float* __restrict__ cb,
                                               float* __restrict__ Bsq,
                                               __bf16* __restrict__ e1) {
    const int k = blockIdx.x * 256 + threadIdx.x;   // 4 blocks -> 1024 codes
    const float* __restrict__ ck = cb + k * CDIM;
    float v[CDIM];
    #pragma unroll
    for (int q = 0; q < 16; ++q) {
        float4 t = ((const float4*)ck)[q];
        v[4 * q + 0] = t.x; v[4 * q + 1] = t.y; v[4 * q + 2] = t.z; v[4 * q + 3] = t.w;
    }
    Bsq[k] = pairwise_sq64(v);

    const int t = k >> 4, kin = k & 15;
    bf16x8* F1 = (bf16x8*)e1;
    #pragma unroll
    for (int ks = 0; ks < 2; ++ks) {
        #pragma unroll
        for (int g = 0; g < 4; ++g) {
            bf16x8 a;
            #pragma unroll
            for (int i = 0; i < 8; ++i) a[i] = (__bf16)v[ks * 32 + 8 * g + i];
            F1[(t * 2 + ks) * 64 + ((g << 4) | kin)] = a;
        }
    }
}

// branchless sorted-3 insert: fmaf + pack + min + 2*med3
#define INS(s, j, accv, Bv, code0) \
    { \
        const float vv = __fmaf_rn(-2.f, (accv), (Bv)); \
        const float kk = __int_as_float((__float_as_int(vv) & 0xFFFFFC00) | (code0)); \
        const float o0 = K0[s][j], o1 = K1[s][j], o2 = K2[s][j]; \
        K0[s][j] = fminf(o0, kk); \
        K1[s][j] = __builtin_amdgcn_fmed3f(o0, o1, kk); \
        K2[s][j] = __builtin_amdgcn_fmed3f(o1, o2, kk); \
    }

// one tile: 4 MFMA (2 per row-set, chained over K) + 8 inserts
#define TILE_COMPUTE(Ea, Eb, code0) \
    { \
        const float Bv = sB[code0]; \
        f32x4 a0 = __builtin_amdgcn_mfma_f32_16x16x32_bf16(zh00, Ea, zero, 0, 0, 0); \
        a0       = __builtin_amdgcn_mfma_f32_16x16x32_bf16(zh01, Eb, a0, 0, 0, 0); \
        f32x4 a1 = __builtin_amdgcn_mfma_f32_16x16x32_bf16(zh10, Ea, zero, 0, 0, 0); \
        a1       = __builtin_amdgcn_mfma_f32_16x16x32_bf16(zh11, Eb, a1, 0, 0, 0); \
        INS(0, 0, a0[0], Bv, code0) INS(0, 1, a0[1], Bv, code0) \
        INS(0, 2, a0[2], Bv, code0) INS(0, 3, a0[3], Bv, code0) \
        INS(1, 0, a1[0], Bv, code0) INS(1, 1, a1[1], Bv, code0) \
        INS(1, 2, a1[2], Bv, code0) INS(1, 3, a1[3], Bv, code0) \
    }

// ---------------- main: k-split MFMA screen + exact rescue ----------------
// Block = 64 rows; wave w: rows [32*(w>>1),+32) x codes [512*(w&1),+512).
__global__ __launch_bounds__(256, 4) void vq_main(const float* __restrict__ z,
                                                  const float* __restrict__ cb,
                                                  const float* __restrict__ Bsq,
                                                  const __bf16* __restrict__ e1,
                                                  float* __restrict__ zq_out,
                                                  float* __restrict__ idx_out,
                                                  double* __restrict__ part) {
    // union: [phase 0/1] 8 frag-planes x 65 slots x 16B = 8320 B
    //        [phase 2]   sKey: 64 rows x 97 floats = 24832 B
    __shared__ __align__(16) unsigned char sU[24832];
    __shared__ float  sB[KCODES];
    __shared__ double sP2[2];

    const int tid = threadIdx.x;
    const int n0 = blockIdx.x * RPB;
    const int b = n0 >> 12;
    const int hw0 = n0 & 4095;
    const float* __restrict__ zb = z + ((size_t)b << 18) + hw0;

    for (int k = tid; k < KCODES; k += 256) sB[k] = Bsq[k];

    // ---- phase 0: cooperative z staging into bf16-hi fragment planes ----
    // plane(wp,s,H) = wp*4 + s*2 + H ; slot = g*16+li ; 65 slots/plane
    {
        bf16x8* __restrict__ zfw = (bf16x8*)sU;
        const int r = tid & 63;              // row 0..63
        const int hh = tid >> 6;             // 0..3
        const int H = hh >> 1, G = hh & 1;   // K-half, g-pair
        const int wp = r >> 5, s = (r >> 4) & 1, li = r & 15;
        #pragma unroll
        for (int gg = 0; gg < 2; ++gg) {
            const int g = G * 2 + gg;
            bf16x8 hi;
            #pragma unroll
            for (int i = 0; i < 8; ++i) {
                const float fv = zb[((size_t)(32 * H + 8 * g + i) << 12) + r];
                hi[i] = (__bf16)fv;
            }
            zfw[(wp * 4 + s * 2 + H) * 65 + ((g << 4) | li)] = hi;
        }
    }
    __syncthreads();

    // ---- phase 1: MFMA screen; wave w: rows [32*wp,+32) x codes [512*kh,+512) ----
    const int lane = tid & 63, w = tid >> 6;
    const int wp = w >> 1, kh = w & 1;
    const int g = lane >> 4, li = lane & 15;

    const bf16x8* __restrict__ zf = (const bf16x8*)sU;
    const bf16x8 zh00 = zf[(wp * 4 + 0) * 65 + lane];   // set0, K-half0
    const bf16x8 zh01 = zf[(wp * 4 + 1) * 65 + lane];   // set0, K-half1
    const bf16x8 zh10 = zf[(wp * 4 + 2) * 65 + lane];   // set1, K-half0
    const bf16x8 zh11 = zf[(wp * 4 + 3) * 65 + lane];   // set1, K-half1

    float K0[2][4], K1[2][4], K2[2][4];
    #pragma unroll
    for (int s = 0; s < 2; ++s)
        #pragma unroll
        for (int j = 0; j < 4; ++j) { K0[s][j] = FLT_BIG; K1[s][j] = FLT_BIG; K2[s][j] = FLT_BIG; }

    const bf16x8* __restrict__ pe1 = (const bf16x8*)e1 + kh * 4096 + lane;
    const f32x4 zero = {0.f, 0.f, 0.f, 0.f};

    // register double-buffer over e1 tiles
    bf16x8 A1a = pe1[0], A1b = pe1[64];
    int tb = (kh << 9) | li;

    for (int t = 0; t < 32; t += 2) {
        const int o1 = (t + 1) * 128;
        const int o2 = (t + 2) * 128;    // at t=30: one-tile overread (pad/adjacent, harmless)
        bf16x8 B1a = pe1[o1], B1b = pe1[o1 + 64];
        TILE_COMPUTE(A1a, A1b, tb)
        A1a = pe1[o2]; A1b = pe1[o2 + 64];
        TILE_COMPUTE(B1a, B1b, tb + 16)
        tb += 32;
    }

    __syncthreads();   // frag planes dead; reuse sU as sKey

    float* __restrict__ sKey = (float*)sU;
    #pragma unroll
    for (int s = 0; s < 2; ++s) {
        #pragma unroll
        for (int j = 0; j < 4; ++j) {
            const int row = 32 * wp + 16 * s + 4 * g + j;   // local row 0..63
            const int base = row * CSTRIDE + kh * 48 + li * 3;
            sKey[base + 0] = K0[s][j];
            sKey[base + 1] = K1[s][j];
            sKey[base + 2] = K2[s][j];
        }
    }
    __syncthreads();

    // ---- phase 2: exact numpy-semantics rescue, one thread per row ----
    if (tid < RPB) {
        const int r = tid;
        const int n = n0 + r;

        float gmin = FLT_BIG;
        #pragma unroll
        for (int s2 = 0; s2 < 96; ++s2) gmin = fminf(gmin, sKey[r * CSTRIDE + s2]);
        const float thr = gmin + DELTA;

        float zrow[CDIM];
        const float* __restrict__ zp = zb + r;
        #pragma unroll
        for (int c = 0; c < CDIM; ++c) zrow[c] = zp[(size_t)c << 12];  // coalesced
        const float A = pairwise_sq64(zrow);

        float bd = FLT_BIG;
        int bk = 1 << 30;
        for (int s2 = 0; s2 < 96; ++s2) {
            const float kv = sKey[r * CSTRIDE + s2];
            if (kv <= thr) {
                const int k = __float_as_int(kv) & 0x3FF;
                const float4* __restrict__ ek = (const float4*)(cb + (size_t)k * CDIM);
                float m = 0.f;
                #pragma unroll
                for (int q = 0; q < 16; ++q) {      // BLAS order: sequential in c
                    float4 e = ek[q];
                    m = __fmaf_rn(zrow[4 * q + 0], e.x, m);
                    m = __fmaf_rn(zrow[4 * q + 1], e.y, m);
                    m = __fmaf_rn(zrow[4 * q + 2], e.z, m);
                    m = __fmaf_rn(zrow[4 * q + 3], e.w, m);
                }
                const float d = __fsub_rn(__fadd_rn(A, sB[k]), __fadd_rn(m, m));
                if (d < bd || (d == bd && k < bk)) { bd = d; bk = k; }
            }
        }

        idx_out[n] = (float)bk;

        const float4* __restrict__ cq = (const float4*)(cb + (size_t)bk * CDIM);
        float* __restrict__ zo = zq_out + ((size_t)b << 18) + hw0 + r;
        float lsum = 0.f;
        #pragma unroll
        for (int q = 0; q < 16; ++q) {
            float4 qv = cq[q];
            zo[(size_t)(4 * q + 0) << 12] = qv.x;
            zo[(size_t)(4 * q + 1) << 12] = qv.y;
            zo[(size_t)(4 * q + 2) << 12] = qv.z;
            zo[(size_t)(4 * q + 3) << 12] = qv.w;
            lsum = fmaf(qv.x - zrow[4 * q + 0], qv.x - zrow[4 * q + 0], lsum);
            lsum = fmaf(qv.y - zrow[4 * q + 1], qv.y - zrow[4 * q + 1], lsum);
            lsum = fmaf(qv.z - zrow[4 * q + 2], qv.z - zrow[4 * q + 2], lsum);
            lsum = fmaf(qv.w - zrow[4 * q + 3], qv.w - zrow[4 * q + 3], lsum);
        }

        double ls = (double)lsum;
        for (int off = 32; off > 0; off >>= 1) ls += __shfl_down(ls, off, 64);
        if (tid == 0) sP2[0] = ls;
    }
    __syncthreads();
    if (tid == 0) part[blockIdx.x] = sP2[0];
}

__global__ void vq_finalize(const double* __restrict__ part, float* __restrict__ loss_out) {
    __shared__ double s[16];
    const int tid = threadIdx.x;       // 1024 threads, one block
    double v = part[tid] + part[tid + 1024];
    for (int off = 32; off > 0; off >>= 1) v += __shfl_down(v, off, 64);
    if ((tid & 63) == 0) s[tid >> 6] = v;
    __syncthreads();
    if (tid == 0) {
        double t = 0.0;
        #pragma unroll
        for (int i = 0; i < 16; ++i) t += s[i];
        // loss = codebook_loss + 0.25*commitment = 1.25 * mean((z_q - z)^2)
        *loss_out = (float)(1.25 * t / (double)ZQ_ELEMS);
    }
}

extern "C" void kernel_launch(void* const* d_in, const int* in_sizes, int n_in,
                              void* d_out, int out_size, void* d_ws, size_t ws_size,
                              hipStream_t stream) {
    const float* z  = (const float*)d_in[0];
    const float* cb = (const float*)d_in[1];
    float* out  = (float*)d_out;
    float* zq   = out;                       // 8388608
    float* loss = out + ZQ_ELEMS;            // 1
    float* idx  = out + ZQ_ELEMS + 1;        // 131072
    char* ws = (char*)d_ws;
    double* part = (double*)ws;              // 2048 doubles (16 KB)
    float* Bsq   = (float*)(ws + WS_BSQ_OFF);
    __bf16* e1   = (__bf16*)(ws + WS_E1_OFF);

    vq_prep<<<4, 256, 0, stream>>>(cb, Bsq, e1);
    vq_main<<<NBLK, 256, 0, stream>>>(z, cb, Bsq, e1, zq, idx, part);
    vq_finalize<<<1, 1024, 0, stream>>>(part, loss);
}

// Round 17
// 75.900 us; speedup vs baseline: 1.3391x; 1.3391x over previous
//
#include <hip/hip_runtime.h>

#define CDIM 64
#define KCODES 1024
#define ZQ_ELEMS (32 * 64 * 64 * 64)  // 8388608
#define NROWS 131072
#define FLT_BIG 3.402823466e38f
#define RPB 64                        // rows per block
#define NBLK (NROWS / RPB)            // 2048
#define CSTRIDE 49                    // sKey row stride (floats); 48 slots used
#define DELTA 5e-4f                   // screen slack; err bound ~2e-4 (z_lo+e_lo dropped)

// ws layout: [0,16KB) part | [16KB,20KB) Bsq | [32KB,+128KB) e1 | +2KB overread pad after
#define WS_BSQ_OFF 16384
#define WS_E1_OFF  32768

// LDS union offsets (bytes): planes 8*65*16=8320 | sKey 64*49*4=12544 | sRd 1024 | sRk 1024
#define SK_RD_OFF 12544
#define SK_RK_OFF (12544 + 1024)
#define SU_BYTES  (12544 + 2048)

typedef __bf16 bf16x8 __attribute__((ext_vector_type(8)));
typedef float  f32x4  __attribute__((ext_vector_type(4)));

// numpy-exact pairwise sum of squares (8 accumulators, numpy pairwise order)
__device__ __forceinline__ float pairwise_sq64(const float* v) {
    float r[8];
    #pragma unroll
    for (int j = 0; j < 8; ++j) r[j] = __fmul_rn(v[j], v[j]);
    #pragma unroll
    for (int m = 1; m < 8; ++m) {
        #pragma unroll
        for (int j = 0; j < 8; ++j)
            r[j] = __fadd_rn(r[j], __fmul_rn(v[8 * m + j], v[8 * m + j]));
    }
    return __fadd_rn(__fadd_rn(__fadd_rn(r[0], r[1]), __fadd_rn(r[2], r[3])),
                     __fadd_rn(__fadd_rn(r[4], r[5]), __fadd_rn(r[6], r[7])));
}

// ---------------- prep: exact code norms + bf16 codebook, B-fragment layout ----
__global__ __launch_bounds__(256) void vq_prep(const float* __restrict__ cb,
                                               float* __restrict__ Bsq,
                                               __bf16* __restrict__ e1) {
    const int k = blockIdx.x * 256 + threadIdx.x;   // 4 blocks -> 1024 codes
    const float* __restrict__ ck = cb + k * CDIM;
    float v[CDIM];
    #pragma unroll
    for (int q = 0; q < 16; ++q) {
        float4 t = ((const float4*)ck)[q];
        v[4 * q + 0] = t.x; v[4 * q + 1] = t.y; v[4 * q + 2] = t.z; v[4 * q + 3] = t.w;
    }
    Bsq[k] = pairwise_sq64(v);

    const int t = k >> 4, kin = k & 15;
    bf16x8* F1 = (bf16x8*)e1;
    #pragma unroll
    for (int ks = 0; ks < 2; ++ks) {
        #pragma unroll
        for (int g = 0; g < 4; ++g) {
            bf16x8 a;
            #pragma unroll
            for (int i = 0; i < 8; ++i) a[i] = (__bf16)v[ks * 32 + 8 * g + i];
            F1[(t * 2 + ks) * 64 + ((g << 4) | kin)] = a;
        }
    }
}

// branchless sorted-3 insert: fmaf + pack + min + 2*med3
#define INS(j, accv, Bv, code0) \
    { \
        const float vv = __fmaf_rn(-2.f, (accv), (Bv)); \
        const float kk = __int_as_float((__float_as_int(vv) & 0xFFFFFC00) | (code0)); \
        const float o0 = K0[j], o1 = K1[j], o2 = K2[j]; \
        K0[j] = fminf(o0, kk); \
        K1[j] = __builtin_amdgcn_fmed3f(o0, o1, kk); \
        K2[j] = __builtin_amdgcn_fmed3f(o1, o2, kk); \
    }

// one tile: 2 MFMA (16 rows, chained over K) + 4 inserts
#define TILE_COMPUTE(Ea, Eb, code0) \
    { \
        const float Bv = sB[code0]; \
        f32x4 a0 = __builtin_amdgcn_mfma_f32_16x16x32_bf16(zA0, Ea, zero, 0, 0, 0); \
        a0       = __builtin_amdgcn_mfma_f32_16x16x32_bf16(zA1, Eb, a0, 0, 0, 0); \
        INS(0, a0[0], Bv, code0) INS(1, a0[1], Bv, code0) \
        INS(2, a0[2], Bv, code0) INS(3, a0[3], Bv, code0) \
    }

// ---------------- main: row-split MFMA screen + 4-way exact rescue ----------------
// Block = 64 rows; wave w owns rows [16w,16w+16) x all 1024 codes.
__global__ __launch_bounds__(256, 4) void vq_main(const float* __restrict__ z,
                                                  const float* __restrict__ cb,
                                                  const float* __restrict__ Bsq,
                                                  const __bf16* __restrict__ e1,
                                                  float* __restrict__ zq_out,
                                                  float* __restrict__ idx_out,
                                                  double* __restrict__ part) {
    // union: [phase 0/1] 8 frag-planes x 65 slots x 16B = 8320 B
    //        [phase 2]   sKey 64x49 f32 | sRd 256 f32 | sRk 256 i32
    __shared__ __align__(16) unsigned char sU[SU_BYTES];
    __shared__ float sB[KCODES];

    const int tid = threadIdx.x;
    const int n0 = blockIdx.x * RPB;
    const int b = n0 >> 12;
    const int hw0 = n0 & 4095;
    const float* __restrict__ zb = z + ((size_t)b << 18) + hw0;

    for (int k = tid; k < KCODES; k += 256) sB[k] = Bsq[k];

    // ---- phase 0: cooperative z staging into bf16-hi fragment planes ----
    // plane(w,H) = w*2+H ; slot = g*16+li holds row 16w+li, K = 32H+8g+i
    {
        bf16x8* __restrict__ zfw = (bf16x8*)sU;
        const int r = tid & 63;              // row 0..63
        const int hh = tid >> 6;             // 0..3
        const int H = hh >> 1, G = hh & 1;
        const int w = r >> 4, li = r & 15;
        #pragma unroll
        for (int gg = 0; gg < 2; ++gg) {
            const int g = G * 2 + gg;
            bf16x8 hi;
            #pragma unroll
            for (int i = 0; i < 8; ++i) {
                const float fv = zb[((size_t)(32 * H + 8 * g + i) << 12) + r];
                hi[i] = (__bf16)fv;
            }
            zfw[(w * 2 + H) * 65 + ((g << 4) | li)] = hi;
        }
    }
    __syncthreads();

    // ---- phase 1: MFMA screen; wave w: 16 rows x 1024 codes ----
    const int lane = tid & 63, w = tid >> 6;
    const int g = lane >> 4, li = lane & 15;

    const bf16x8* __restrict__ zf = (const bf16x8*)sU;
    const bf16x8 zA0 = zf[(w * 2 + 0) * 65 + lane];   // K 0..31
    const bf16x8 zA1 = zf[(w * 2 + 1) * 65 + lane];   // K 32..63

    float K0[4], K1[4], K2[4];
    #pragma unroll
    for (int j = 0; j < 4; ++j) { K0[j] = FLT_BIG; K1[j] = FLT_BIG; K2[j] = FLT_BIG; }

    const bf16x8* __restrict__ pe1 = (const bf16x8*)e1 + lane;
    const f32x4 zero = {0.f, 0.f, 0.f, 0.f};

    // register double-buffer over e1 tiles (4 bf16x8 live)
    bf16x8 A1a = pe1[0], A1b = pe1[64];
    int tb = li;

    for (int t = 0; t < 64; t += 2) {
        const int o1 = (t + 1) * 128;
        const int o2 = (t + 2) * 128;    // at t=62: one-tile overread into pad (harmless)
        bf16x8 B1a = pe1[o1], B1b = pe1[o1 + 64];
        TILE_COMPUTE(A1a, A1b, tb)
        A1a = pe1[o2]; A1b = pe1[o2 + 64];
        TILE_COMPUTE(B1a, B1b, tb + 16)
        tb += 32;
    }

    __syncthreads();   // frag planes dead; reuse sU as sKey + combine arrays

    float* __restrict__ sKey = (float*)sU;
    float* __restrict__ sRd = (float*)(sU + SK_RD_OFF);
    int*   __restrict__ sRk = (int*)(sU + SK_RK_OFF);
    #pragma unroll
    for (int j = 0; j < 4; ++j) {
        const int row = 16 * w + 4 * g + j;            // local row 0..63
        const int base = row * CSTRIDE + li * 3;
        sKey[base + 0] = K0[j];
        sKey[base + 1] = K1[j];
        sKey[base + 2] = K2[j];
    }
    __syncthreads();

    // ---- phase 2: exact numpy-semantics rescue; 4 threads per row ----
    const int r = tid & 63;
    const int quarter = tid >> 6;
    const int n = n0 + r;

    float gmin = FLT_BIG;
    #pragma unroll
    for (int s2 = 0; s2 < 48; ++s2) gmin = fminf(gmin, sKey[r * CSTRIDE + s2]);
    const float thr = gmin + DELTA;

    float zrow[CDIM];
    const float* __restrict__ zp = zb + r;
    #pragma unroll
    for (int c = 0; c < CDIM; ++c) zrow[c] = zp[(size_t)c << 12];  // coalesced per quarter
    const float A = pairwise_sq64(zrow);

    float bd = FLT_BIG;
    int bk = 1 << 30;
    const int sbeg = quarter * 12;
    for (int s2 = sbeg; s2 < sbeg + 12; ++s2) {
        const float kv = sKey[r * CSTRIDE + s2];
        if (kv <= thr) {
            const int k = __float_as_int(kv) & 0x3FF;
            const float4* __restrict__ ek = (const float4*)(cb + (size_t)k * CDIM);
            float m = 0.f;
            #pragma unroll
            for (int q = 0; q < 16; ++q) {      // BLAS order: sequential in c
                float4 e = ek[q];
                m = __fmaf_rn(zrow[4 * q + 0], e.x, m);
                m = __fmaf_rn(zrow[4 * q + 1], e.y, m);
                m = __fmaf_rn(zrow[4 * q + 2], e.z, m);
                m = __fmaf_rn(zrow[4 * q + 3], e.w, m);
            }
            const float d = __fsub_rn(__fadd_rn(A, sB[k]), __fadd_rn(m, m));
            if (d < bd || (d == bd && k < bk)) { bd = d; bk = k; }
        }
    }

    sRd[tid] = bd;
    sRk[tid] = bk;
    __syncthreads();

    if (tid < RPB) {
        #pragma unroll
        for (int qq = 1; qq < 4; ++qq) {
            const float d2 = sRd[qq * 64 + r];
            const int   k2 = sRk[qq * 64 + r];
            if (d2 < bd || (d2 == bd && k2 < bk)) { bd = d2; bk = k2; }  // lex-min
        }

        idx_out[n] = (float)bk;

        const float4* __restrict__ cq = (const float4*)(cb + (size_t)bk * CDIM);
        float* __restrict__ zo = zq_out + ((size_t)b << 18) + hw0 + r;
        float lsum = 0.f;
        #pragma unroll
        for (int q = 0; q < 16; ++q) {
            float4 qv = cq[q];
            zo[(size_t)(4 * q + 0) << 12] = qv.x;
            zo[(size_t)(4 * q + 1) << 12] = qv.y;
            zo[(size_t)(4 * q + 2) << 12] = qv.z;
            zo[(size_t)(4 * q + 3) << 12] = qv.w;
            lsum = fmaf(qv.x - zrow[4 * q + 0], qv.x - zrow[4 * q + 0], lsum);
            lsum = fmaf(qv.y - zrow[4 * q + 1], qv.y - zrow[4 * q + 1], lsum);
            lsum = fmaf(qv.z - zrow[4 * q + 2], qv.z - zrow[4 * q + 2], lsum);
            lsum = fmaf(qv.w - zrow[4 * q + 3], qv.w - zrow[4 * q + 3], lsum);
        }

        double ls = (double)lsum;
        for (int off = 32; off > 0; off >>= 1) ls += __shfl_down(ls, off, 64);
        if (tid == 0) part[blockIdx.x] = ls;      // single wave -> direct write
    }
}

__global__ void vq_finalize(const double* __restrict__ part, float* __restrict__ loss_out) {
    __shared__ double s[16];
    const int tid = threadIdx.x;       // 1024 threads, one block
    double v = part[tid] + part[tid + 1024];
    for (int off = 32; off > 0; off >>= 1) v += __shfl_down(v, off, 64);
    if ((tid & 63) == 0) s[tid >> 6] = v;
    __syncthreads();
    if (tid == 0) {
        double t = 0.0;
        #pragma unroll
        for (int i = 0; i < 16; ++i) t += s[i];
        // loss = codebook_loss + 0.25*commitment = 1.25 * mean((z_q - z)^2)
        *loss_out = (float)(1.25 * t / (double)ZQ_ELEMS);
    }
}

extern "C" void kernel_launch(void* const* d_in, const int* in_sizes, int n_in,
                              void* d_out, int out_size, void* d_ws, size_t ws_size,
                              hipStream_t stream) {
    const float* z  = (const float*)d_in[0];
    const float* cb = (const float*)d_in[1];
    float* out  = (float*)d_out;
    float* zq   = out;                       // 8388608
    float* loss = out + ZQ_ELEMS;            // 1
    float* idx  = out + ZQ_ELEMS + 1;        // 131072
    char* ws = (char*)d_ws;
    double* part = (double*)ws;              // 2048 doubles (16 KB)
    float* Bsq   = (float*)(ws + WS_BSQ_OFF);
    __bf16* e1   = (__bf16*)(ws + WS_E1_OFF);

    vq_prep<<<4, 256, 0, stream>>>(cb, Bsq, e1);
    vq_main<<<NBLK, 256, 0, stream>>>(z, cb, Bsq, e1, zq, idx, part);
    vq_finalize<<<1, 1024, 0, stream>>>(part, loss);
}

// Round 18
// 69.314 us; speedup vs baseline: 1.4663x; 1.0950x over previous
//
#include <hip/hip_runtime.h>

#define CDIM 64
#define KCODES 1024
#define ZQ_ELEMS (32 * 64 * 64 * 64)  // 8388608
#define NROWS 131072
#define FLT_BIG 3.402823466e38f
#define RPB 128                       // rows per block
#define NBLK (NROWS / RPB)            // 1024
#define CSTRIDE 49                    // sKey row stride (floats); 48 slots used
#define DELTA 5e-4f                   // screen slack; err bound ~2e-4 (z_lo+e_lo dropped)

// ws layout: [0,8KB) part | [16KB,20KB) Bsq | [32KB,+128KB) e1
#define WS_BSQ_OFF 16384
#define WS_E1_OFF  32768

// LDS union (bytes):
//  region A [0, 27136): phase1 frags 16*65*16=16640  ∪  phase2 sKey 128*49*4=25088 | sRd 512 | sRk 512
#define SK_RD_OFF 25088
#define SK_RK_OFF (25088 + 1024)
#define E_OFF     27136               // e-dbuf: 2 x 4096
#define B_OFF     (27136 + 8192)      // sB: 4096
#define SU_BYTES  (27136 + 8192 + 4096)   // 39424 -> 4 blocks/CU

typedef __bf16 bf16x8 __attribute__((ext_vector_type(8)));
typedef float  f32x4  __attribute__((ext_vector_type(4)));

// numpy-exact pairwise sum of squares (8 accumulators, numpy pairwise order)
__device__ __forceinline__ float pairwise_sq64(const float* v) {
    float r[8];
    #pragma unroll
    for (int j = 0; j < 8; ++j) r[j] = __fmul_rn(v[j], v[j]);
    #pragma unroll
    for (int m = 1; m < 8; ++m) {
        #pragma unroll
        for (int j = 0; j < 8; ++j)
            r[j] = __fadd_rn(r[j], __fmul_rn(v[8 * m + j], v[8 * m + j]));
    }
    return __fadd_rn(__fadd_rn(__fadd_rn(r[0], r[1]), __fadd_rn(r[2], r[3])),
                     __fadd_rn(__fadd_rn(r[4], r[5]), __fadd_rn(r[6], r[7])));
}

// ---------------- prep: exact code norms + bf16 codebook, B-fragment layout ----
__global__ __launch_bounds__(256) void vq_prep(const float* __restrict__ cb,
                                               float* __restrict__ Bsq,
                                               __bf16* __restrict__ e1) {
    const int k = blockIdx.x * 256 + threadIdx.x;   // 4 blocks -> 1024 codes
    const float* __restrict__ ck = cb + k * CDIM;
    float v[CDIM];
    #pragma unroll
    for (int q = 0; q < 16; ++q) {
        float4 t = ((const float4*)ck)[q];
        v[4 * q + 0] = t.x; v[4 * q + 1] = t.y; v[4 * q + 2] = t.z; v[4 * q + 3] = t.w;
    }
    Bsq[k] = pairwise_sq64(v);

    const int t = k >> 4, kin = k & 15;
    bf16x8* F1 = (bf16x8*)e1;
    #pragma unroll
    for (int ks = 0; ks < 2; ++ks) {
        #pragma unroll
        for (int g = 0; g < 4; ++g) {
            bf16x8 a;
            #pragma unroll
            for (int i = 0; i < 8; ++i) a[i] = (__bf16)v[ks * 32 + 8 * g + i];
            F1[(t * 2 + ks) * 64 + ((g << 4) | kin)] = a;
        }
    }
}

// branchless sorted-3 insert: fmaf + pack + min + 2*med3
#define INS(s, j, accv, Bv, code0) \
    { \
        const float vv = __fmaf_rn(-2.f, (accv), (Bv)); \
        const float kk = __int_as_float((__float_as_int(vv) & 0xFFFFFC00) | (code0)); \
        const float o0 = K0[s][j], o1 = K1[s][j], o2 = K2[s][j]; \
        K0[s][j] = fminf(o0, kk); \
        K1[s][j] = __builtin_amdgcn_fmed3f(o0, o1, kk); \
        K2[s][j] = __builtin_amdgcn_fmed3f(o1, o2, kk); \
    }

// one 16-code tile: 4 MFMA (2 row-sets, chained over K) + 8 inserts; e from LDS
#define TILE_COMPUTE(Ea, Eb, code0) \
    { \
        const float Bv = sB[code0]; \
        f32x4 a0 = __builtin_amdgcn_mfma_f32_16x16x32_bf16(zh00, Ea, zero, 0, 0, 0); \
        a0       = __builtin_amdgcn_mfma_f32_16x16x32_bf16(zh01, Eb, a0, 0, 0, 0); \
        f32x4 a1 = __builtin_amdgcn_mfma_f32_16x16x32_bf16(zh10, Ea, zero, 0, 0, 0); \
        a1       = __builtin_amdgcn_mfma_f32_16x16x32_bf16(zh11, Eb, a1, 0, 0, 0); \
        INS(0, 0, a0[0], Bv, code0) INS(0, 1, a0[1], Bv, code0) \
        INS(0, 2, a0[2], Bv, code0) INS(0, 3, a0[3], Bv, code0) \
        INS(1, 0, a1[0], Bv, code0) INS(1, 1, a1[1], Bv, code0) \
        INS(1, 2, a1[2], Bv, code0) INS(1, 3, a1[3], Bv, code0) \
    }

// ---------------- main: MFMA screen with LDS-dbuf e-stream + exact rescue ----------------
// Block = 128 rows (4 waves x 32 rows); codes streamed in 32-code chunks via LDS dbuf.
__global__ __launch_bounds__(256, 4) void vq_main(const float* __restrict__ z,
                                                  const float* __restrict__ cb,
                                                  const float* __restrict__ Bsq,
                                                  const __bf16* __restrict__ e1,
                                                  float* __restrict__ zq_out,
                                                  float* __restrict__ idx_out,
                                                  double* __restrict__ part) {
    __shared__ __align__(16) unsigned char sU[SU_BYTES];
    __shared__ double sP2[2];
    float* __restrict__ sB = (float*)(sU + B_OFF);

    const int tid = threadIdx.x;
    const int n0 = blockIdx.x * RPB;
    const int b = n0 >> 12;
    const int hw0 = n0 & 4095;
    const float* __restrict__ zb = z + ((size_t)b << 18) + hw0;

    for (int k = tid; k < KCODES; k += 256) sB[k] = Bsq[k];

    // ---- phase 0: z staging into bf16-hi fragment planes + e-chunk 0 ----
    // plane(w,s,H) = w*4+s*2+H ; slot = g*16+li ; row=32w+16s+li ; K=32H+8g+i
    {
        bf16x8* __restrict__ zfw = (bf16x8*)sU;
        const int r = tid & 127;             // row
        const int h = tid >> 7;              // K half
        const int w = r >> 5, s = (r >> 4) & 1, li = r & 15;
        #pragma unroll
        for (int g = 0; g < 4; ++g) {
            bf16x8 hi;
            #pragma unroll
            for (int i = 0; i < 8; ++i) {
                const float fv = zb[((size_t)(32 * h + 8 * g + i) << 12) + r];
                hi[i] = (__bf16)fv;
            }
            zfw[(w * 4 + s * 2 + h) * 65 + ((g << 4) | li)] = hi;
        }
        // stage e chunk 0 (4 KB, coalesced)
        *(float4*)(sU + E_OFF + tid * 16) =
            *(const float4*)((const unsigned char*)e1 + tid * 16);
    }
    __syncthreads();

    // ---- phase 1: MFMA screen; wave w owns rows [32w,32w+32) x all 1024 codes ----
    const int lane = tid & 63, w = tid >> 6;
    const int g = lane >> 4, li = lane & 15;

    const bf16x8* __restrict__ zf = (const bf16x8*)sU;
    const bf16x8 zh00 = zf[(w * 4 + 0) * 65 + lane];
    const bf16x8 zh01 = zf[(w * 4 + 1) * 65 + lane];
    const bf16x8 zh10 = zf[(w * 4 + 2) * 65 + lane];
    const bf16x8 zh11 = zf[(w * 4 + 3) * 65 + lane];

    float K0[2][4], K1[2][4], K2[2][4];
    #pragma unroll
    for (int s = 0; s < 2; ++s)
        #pragma unroll
        for (int j = 0; j < 4; ++j) { K0[s][j] = FLT_BIG; K1[s][j] = FLT_BIG; K2[s][j] = FLT_BIG; }

    const f32x4 zero = {0.f, 0.f, 0.f, 0.f};

    // LDS double-buffered e-stream: chunk = 32 codes = 2 tiles = 4 KB
    for (int c = 0; c < 32; ++c) {
        float4 vstage;
        if (c < 31) {
            vstage = *(const float4*)((const unsigned char*)e1 + (c + 1) * 4096 + tid * 16);
        }
        const bf16x8* __restrict__ buf = (const bf16x8*)(sU + E_OFF + (c & 1) * 4096);
        const int cb0 = c * 32 + li;
        TILE_COMPUTE(buf[lane],       buf[64 + lane],  cb0)
        TILE_COMPUTE(buf[128 + lane], buf[192 + lane], cb0 + 16)
        if (c < 31) {
            *(float4*)(sU + E_OFF + ((c + 1) & 1) * 4096 + tid * 16) = vstage;
        }
        __syncthreads();
    }

    // frag planes + e-dbuf dead; reuse region A as sKey + combine arrays
    float* __restrict__ sKey = (float*)sU;
    float* __restrict__ sRd = (float*)(sU + SK_RD_OFF);
    int*   __restrict__ sRk = (int*)(sU + SK_RK_OFF);
    #pragma unroll
    for (int s = 0; s < 2; ++s) {
        #pragma unroll
        for (int j = 0; j < 4; ++j) {
            const int row = 32 * w + 16 * s + 4 * g + j;   // local row 0..127
            const int base = row * CSTRIDE + li * 3;
            sKey[base + 0] = K0[s][j];
            sKey[base + 1] = K1[s][j];
            sKey[base + 2] = K2[s][j];
        }
    }
    __syncthreads();

    // ---- phase 2: exact numpy-semantics rescue; 2 threads per row ----
    {
        const int r = tid & 127;
        const int half = tid >> 7;
        const int n = n0 + r;

        float gmin = FLT_BIG;
        #pragma unroll
        for (int s2 = 0; s2 < 48; ++s2) gmin = fminf(gmin, sKey[r * CSTRIDE + s2]);
        const float thr = gmin + DELTA;

        float zrow[CDIM];
        const float* __restrict__ zp = zb + r;
        #pragma unroll
        for (int c = 0; c < CDIM; ++c) zrow[c] = zp[(size_t)c << 12];  // coalesced, L1/L2-hot
        const float A = pairwise_sq64(zrow);

        float bd = FLT_BIG;
        int bk = 1 << 30;
        const int sbeg = half * 24;
        for (int s2 = sbeg; s2 < sbeg + 24; ++s2) {
            const float kv = sKey[r * CSTRIDE + s2];
            if (kv <= thr) {
                const int k = __float_as_int(kv) & 0x3FF;
                const float4* __restrict__ ek = (const float4*)(cb + (size_t)k * CDIM);
                float m = 0.f;
                #pragma unroll
                for (int q = 0; q < 16; ++q) {      // BLAS order: sequential in c
                    float4 e = ek[q];
                    m = __fmaf_rn(zrow[4 * q + 0], e.x, m);
                    m = __fmaf_rn(zrow[4 * q + 1], e.y, m);
                    m = __fmaf_rn(zrow[4 * q + 2], e.z, m);
                    m = __fmaf_rn(zrow[4 * q + 3], e.w, m);
                }
                const float d = __fsub_rn(__fadd_rn(A, sB[k]), __fadd_rn(m, m));
                if (d < bd || (d == bd && k < bk)) { bd = d; bk = k; }
            }
        }

        if (half == 1) { sRd[r] = bd; sRk[r] = bk; }
        __syncthreads();

        if (tid < RPB) {
            const float d1 = sRd[r];
            const int   k1 = sRk[r];
            if (d1 < bd || (d1 == bd && k1 < bk)) { bd = d1; bk = k1; }  // lex-min combine

            idx_out[n] = (float)bk;

            const float4* __restrict__ cq = (const float4*)(cb + (size_t)bk * CDIM);
            float* __restrict__ zo = zq_out + ((size_t)b << 18) + hw0 + r;
            float lsum = 0.f;
            #pragma unroll
            for (int q = 0; q < 16; ++q) {
                float4 qv = cq[q];
                zo[(size_t)(4 * q + 0) << 12] = qv.x;
                zo[(size_t)(4 * q + 1) << 12] = qv.y;
                zo[(size_t)(4 * q + 2) << 12] = qv.z;
                zo[(size_t)(4 * q + 3) << 12] = qv.w;
                lsum = fmaf(qv.x - zrow[4 * q + 0], qv.x - zrow[4 * q + 0], lsum);
                lsum = fmaf(qv.y - zrow[4 * q + 1], qv.y - zrow[4 * q + 1], lsum);
                lsum = fmaf(qv.z - zrow[4 * q + 2], qv.z - zrow[4 * q + 2], lsum);
                lsum = fmaf(qv.w - zrow[4 * q + 3], qv.w - zrow[4 * q + 3], lsum);
            }

            double ls = (double)lsum;
            for (int off = 32; off > 0; off >>= 1) ls += __shfl_down(ls, off, 64);
            if ((tid & 63) == 0) sP2[tid >> 6] = ls;
        }
    }
    __syncthreads();
    if (tid == 0) part[blockIdx.x] = sP2[0] + sP2[1];
}

__global__ void vq_finalize(const double* __restrict__ part, float* __restrict__ loss_out) {
    __shared__ double s[16];
    const int tid = threadIdx.x;       // 1024 threads, one block
    double v = part[tid];
    for (int off = 32; off > 0; off >>= 1) v += __shfl_down(v, off, 64);
    if ((tid & 63) == 0) s[tid >> 6] = v;
    __syncthreads();
    if (tid == 0) {
        double t = 0.0;
        #pragma unroll
        for (int i = 0; i < 16; ++i) t += s[i];
        // loss = codebook_loss + 0.25*commitment = 1.25 * mean((z_q - z)^2)
        *loss_out = (float)(1.25 * t / (double)ZQ_ELEMS);
    }
}

extern "C" void kernel_launch(void* const* d_in, const int* in_sizes, int n_in,
                              void* d_out, int out_size, void* d_ws, size_t ws_size,
                              hipStream_t stream) {
    const float* z  = (const float*)d_in[0];
    const float* cb = (const float*)d_in[1];
    float* out  = (float*)d_out;
    float* zq   = out;                       // 8388608
    float* loss = out + ZQ_ELEMS;            // 1
    float* idx  = out + ZQ_ELEMS + 1;        // 131072
    char* ws = (char*)d_ws;
    double* part = (double*)ws;              // 1024 doubles
    float* Bsq   = (float*)(ws + WS_BSQ_OFF);
    __bf16* e1   = (__bf16*)(ws + WS_E1_OFF);

    vq_prep<<<4, 256, 0, stream>>>(cb, Bsq, e1);
    vq_main<<<NBLK, 256, 0, stream>>>(z, cb, Bsq, e1, zq, idx, part);
    vq_finalize<<<1, 1024, 0, stream>>>(part, loss);
}